// Round 13
// baseline (24610.323 us; speedup 1.0000x reference)
//
#include <hip/hip_runtime.h>
#include <math.h>

#define Bz 16
#define Tz 1024
#define Ez 768
#define E3 2304
#define Vz 50257
#define NBK 256          // 256 blocks: 128 layer-0, 128 layer-1, 6 columns each
#define LN_EPS 1e-5f
#define VEC (Bz*Ez)      // 12288 floats per h vector
#define EP 772           // padded LDS row stride

__device__ __forceinline__ float dot4acc(float acc, float4 w, float4 h){
  acc = fmaf(w.x,h.x,acc); acc = fmaf(w.y,h.y,acc);
  acc = fmaf(w.z,h.z,acc); acc = fmaf(w.w,h.w,acc);
  return acc;
}
__device__ __forceinline__ float sigm(float x){ return 1.0f/(1.0f+expf(-x)); }

// ---- Staging envelope (empirical, 5 failed probes + 2 passes):
//   SAFE:   scalar 32-bit relaxed-atomic loads, IMMEDIATE LDS store per body,
//           up to (now) 4 independent streams per body.
//   CURSED: u64 atomics, batch-then-store (8/16-deep), inline-asm loads,
//           global_load_lds DMA  -> all-zero output signature.
// This round: 4-wide immediate-store bodies (was 2-wide in passing R12). ----

// One 12288-float vector, 512 threads, 24 els/thread = 6 bodies x 4 streams.
__device__ __forceinline__ void stage_one(const float* __restrict__ src,
                                          float (*dst)[EP], int tid){
#pragma unroll
  for (int k=0;k<6;k++){
    const int u0 = tid + (k<<9);
    const int u1 = u0 + 3072;
    const int u2 = u0 + 6144;
    const int u3 = u0 + 9216;
    const float a0 = __hip_atomic_load(src+u0, __ATOMIC_RELAXED, __HIP_MEMORY_SCOPE_AGENT);
    const float a1 = __hip_atomic_load(src+u1, __ATOMIC_RELAXED, __HIP_MEMORY_SCOPE_AGENT);
    const float a2 = __hip_atomic_load(src+u2, __ATOMIC_RELAXED, __HIP_MEMORY_SCOPE_AGENT);
    const float a3 = __hip_atomic_load(src+u3, __ATOMIC_RELAXED, __HIP_MEMORY_SCOPE_AGENT);
    const int b0=u0/768, c0_=u0-b0*768;  dst[b0][c0_]=a0;
    const int b1=u1/768, c1_=u1-b1*768;  dst[b1][c1_]=a1;
    const int b2=u2/768, c2_=u2-b2*768;  dst[b2][c2_]=a2;
    const int b3=u3/768, c3_=u3-b3*768;  dst[b3][c3_]=a3;
  }
}

// Two vectors -> two buffers, 12 bodies of 4 streams (2 per vector).
__device__ __forceinline__ void stage_two(const float* __restrict__ srcX,
                                          float (*dstX)[EP],
                                          const float* __restrict__ srcH,
                                          float (*dstH)[EP], int tid){
#pragma unroll
  for (int k=0;k<12;k++){
    const int u0 = tid + (k<<9);
    const int u1 = u0 + 6144;
    const float x0 = __hip_atomic_load(srcX+u0, __ATOMIC_RELAXED, __HIP_MEMORY_SCOPE_AGENT);
    const float x1 = __hip_atomic_load(srcX+u1, __ATOMIC_RELAXED, __HIP_MEMORY_SCOPE_AGENT);
    const float h0 = __hip_atomic_load(srcH+u0, __ATOMIC_RELAXED, __HIP_MEMORY_SCOPE_AGENT);
    const float h1 = __hip_atomic_load(srcH+u1, __ATOMIC_RELAXED, __HIP_MEMORY_SCOPE_AGENT);
    const int b0=u0/768, c0_=u0-b0*768;
    const int b1=u1/768, c1_=u1-b1*768;
    dstX[b0][c0_]=x0;  dstX[b1][c1_]=x1;
    dstH[b0][c0_]=h0;  dstH[b1][c1_]=h1;
  }
}

__device__ __forceinline__ void zero_buf(float (*dst)[EP], int tid){
#pragma unroll
  for (int k=0;k<24;k++){
    const int u = tid + (k<<9);
    const int b = u/768, c = u - b*768;
    dst[b][c] = 0.f;
  }
}

// ---------------------------------------------------------------------------
// Persistent cooperative scan; layer-skewed (L0 computes h0(s), L1 computes
// h1(s-1) in super-step s). Two-level STORE-ONLY barrier (proven R7/R12):
//   arrive: flags[bx]=s+1 ; block 0 aggregates -> go=s ; others poll go.
// All atomics 32-bit relaxed agent scope; publish stores vmcnt-drained by
// the pre-barrier syncthreads before the flag store.
// ---------------------------------------------------------------------------
__global__ __launch_bounds__(512) void gru_scan(
    const int* __restrict__ idx, const float* __restrict__ wte,
    const float* __restrict__ Wih, const float* __restrict__ bih,
    const float* __restrict__ Whh, const float* __restrict__ bhh,
    float* __restrict__ h0g, float* __restrict__ h1g,
    unsigned* __restrict__ flags, unsigned* __restrict__ go)
{
  __shared__ float bufX0[Bz][EP];   // L0: x(t) ping   | L1: h0(t)
  __shared__ float bufX1[Bz][EP];   // L0: x(t) pong   | L1: unused
  __shared__ float bufH [Bz][EP];   // h_prev (own layer)
  __shared__ float gates[36][17];   // [row m][batch]
  __shared__ float biasS[36];

  const int tid = threadIdx.x, bx = blockIdx.x;
  const int L = bx>>7, sub = bx&127, c0 = sub*6;
  const int wv = tid>>6, lane = tid&63, kq = lane&15, bb = lane>>4;

  const float* WihL = Wih + (size_t)L*E3*Ez;
  const float* WhhL = Whh + (size_t)L*E3*Ez;

  // 9 weight-row pointers per wave (meaningful for tid<256 / wv<4 only).
  const float* wrow[9];
#pragma unroll
  for (int r=0;r<9;r++){
    const int m = (wv&3)*9+r, mat = m/18, mm = m%18, g = mm/6, cc = mm-g*6;
    wrow[r] = (mat ? WhhL : WihL) + (size_t)(g*Ez + c0 + cc)*Ez;
  }
  if (tid<36){
    const int mat = tid/18, mm = tid%18, g = mm/6, cc = mm-g*6;
    biasS[tid] = (mat ? bhh : bih)[L*E3 + g*Ez + c0 + cc];
  }

  // preload x(0) for layer 0 (512 threads x 6 float4)
  if (L==0){
#pragma unroll
    for (int k4=0;k4<6;k4++){
      const int i4 = tid + (k4<<9);
      const int b = i4/192, c4 = i4 - b*192;
      const int row = idx[b*Tz];
      *(float4*)&bufX0[b][c4<<2] = *(const float4*)(wte + (size_t)row*Ez + (c4<<2));
    }
  }
  __syncthreads();

  for (int s=0; s<=Tz; ++s){
    // ---- grid wait ----
    if (s>0){
      const unsigned tgt = (unsigned)s;
      if (bx==0){
        if (tid<64){
          const unsigned* f = flags + (tid<<2);
          for(;;){
            const unsigned a0 = __hip_atomic_load(f+0, __ATOMIC_RELAXED, __HIP_MEMORY_SCOPE_AGENT);
            const unsigned a1 = __hip_atomic_load(f+1, __ATOMIC_RELAXED, __HIP_MEMORY_SCOPE_AGENT);
            const unsigned a2 = __hip_atomic_load(f+2, __ATOMIC_RELAXED, __HIP_MEMORY_SCOPE_AGENT);
            const unsigned a3 = __hip_atomic_load(f+3, __ATOMIC_RELAXED, __HIP_MEMORY_SCOPE_AGENT);
            const int ok = (a0>=tgt) & (a1>=tgt) & (a2>=tgt) & (a3>=tgt);
            if (__all(ok)) break;
            __builtin_amdgcn_s_sleep(1);
          }
          if (tid==0)
            __hip_atomic_store(go, tgt, __ATOMIC_RELAXED, __HIP_MEMORY_SCOPE_AGENT);
        }
      } else {
        if (tid==0){
          while (__hip_atomic_load(go, __ATOMIC_RELAXED, __HIP_MEMORY_SCOPE_AGENT) < tgt)
            __builtin_amdgcn_s_sleep(1);
        }
      }
      __syncthreads();
    }

    const bool active = (L==0) ? (s<Tz) : (s>0);
    if (active){
      const int t = (L==0) ? s : s-1;

      // ---- stage phase (512 threads, 4-wide immediate-store bodies) ----
      if (L==0){
        if (t==0) zero_buf(bufH, tid);
        else      stage_one(h0g + (size_t)((s-1)&1)*VEC, bufH, tid);
      } else {
        if (t==0){
          stage_one(h0g + (size_t)((s-1)&1)*VEC, bufX0, tid);
          zero_buf(bufH, tid);
        } else {
          stage_two(h0g + (size_t)((s-1)&1)*VEC, bufX0,
                    h1g + (size_t)(s&1)*VEC,     bufH, tid);
        }
      }
      __syncthreads();

      // ---- matmul on waves 0-3 only ----
      if (tid < 256){
        const float (*V)[EP];
        if (wv<2) V = (L==0) ? ((s&1) ? bufX1 : bufX0) : bufX0;
        else      V = bufH;

        float acc[9][4];
#pragma unroll
        for (int r=0;r<9;r++)
#pragma unroll
          for (int bi=0;bi<4;bi++) acc[r][bi]=0.f;

#pragma unroll 4
        for (int j=0;j<12;j++){
          const int kk = (j<<6) + (kq<<2);
          float4 wv4[9];
#pragma unroll
          for (int r=0;r<9;r++) wv4[r] = *(const float4*)(wrow[r] + kk);
#pragma unroll
          for (int bi=0;bi<4;bi++){
            const float4 hv = *(const float4*)&V[bb*4+bi][kk];
#pragma unroll
            for (int r=0;r<9;r++) acc[r][bi] = dot4acc(acc[r][bi], wv4[r], hv);
          }
        }
#pragma unroll
        for (int r=0;r<9;r++)
#pragma unroll
          for (int bi=0;bi<4;bi++){
            float a = acc[r][bi];
            a += __shfl_xor(a,1); a += __shfl_xor(a,2);
            a += __shfl_xor(a,4); a += __shfl_xor(a,8);
            acc[r][bi]=a;
          }
        if (kq==0){
#pragma unroll
          for (int r=0;r<9;r++)
#pragma unroll
            for (int bi=0;bi<4;bi++) gates[wv*9+r][bb*4+bi] = acc[r][bi];
        }
      }
      __syncthreads();

      // ---- nonlinearity + publish h-slice (96 threads: 16 b x 6 cols) ----
      if (tid < 96){
        const int b = tid&15, cc = tid>>4;
        const float gir = gates[cc   ][b] + biasS[cc];
        const float giz = gates[6+cc ][b] + biasS[6+cc];
        const float gin = gates[12+cc][b] + biasS[12+cc];
        const float ghr = gates[18+cc][b] + biasS[18+cc];
        const float ghz = gates[24+cc][b] + biasS[24+cc];
        const float ghn = gates[30+cc][b] + biasS[30+cc];
        const float r = sigm(gir+ghr);
        const float z = sigm(giz+ghz);
        const float n = tanhf(fmaf(r, ghn, gin));
        const float hp = bufH[b][c0+cc];
        const float hv = fmaf(z, hp - n, n);
        float* hOut = (L==0) ? (h0g + (size_t)(s&1)*VEC)
                             : (h1g + (size_t)((s-1)&1)*VEC);
        __hip_atomic_store(hOut + b*Ez + c0 + cc, hv,
                           __ATOMIC_RELAXED, __HIP_MEMORY_SCOPE_AGENT);
      }
    }

    // ---- arrive: syncthreads drains vmcnt (h stores at L3), then flag ----
    __syncthreads();
    if (tid==0)
      __hip_atomic_store(flags + bx, (unsigned)(s+1),
                         __ATOMIC_RELAXED, __HIP_MEMORY_SCOPE_AGENT);

    // ---- prefetch x(s+1) AFTER arrive (off the barrier critical path) ----
    if (L==0 && active && s+1 < Tz){
      float (*bx_)[EP] = ((s+1)&1) ? bufX1 : bufX0;
#pragma unroll
      for (int k4=0;k4<6;k4++){
        const int i4 = tid + (k4<<9);
        const int b = i4/192, c4 = i4 - b*192;
        const int row = idx[b*Tz + (s+1)];
        *(float4*)&bx_[b][c4<<2] = *(const float4*)(wte + (size_t)row*Ez + (c4<<2));
      }
    }
  }
}

// LayerNorm of final h1 -> ln
__global__ __launch_bounds__(256) void finalize_ln(
    const float* __restrict__ h1, const float* __restrict__ g,
    float* __restrict__ ln)
{
  const int tid=threadIdx.x, wv=tid>>6, lane=tid&63;
  for (int b=wv; b<Bz; b+=4){
    float sum=0.f;
    for (int c=lane;c<Ez;c+=64) sum += h1[b*Ez+c];
#pragma unroll
    for (int off=32; off; off>>=1) sum += __shfl_xor(sum, off);
    const float mu = sum/(float)Ez;
    float s2=0.f;
    for (int c=lane;c<Ez;c+=64){ const float d=h1[b*Ez+c]-mu; s2=fmaf(d,d,s2); }
#pragma unroll
    for (int off=32; off; off>>=1) s2 += __shfl_xor(s2, off);
    const float inv = rsqrtf(s2/(float)Ez + LN_EPS);
    for (int c=lane;c<Ez;c+=64) ln[b*Ez+c] = (h1[b*Ez+c]-mu)*inv*g[c];
  }
}

// logits[b,v] = dot(ln[b,:], wte[v,:]) ; 64 rows per block, 16 rows per wave.
__global__ __launch_bounds__(256) void lm_head(
    const float* __restrict__ ln, const float* __restrict__ wte,
    float* __restrict__ out)
{
  __shared__ float sLn[Bz][EP];
  const int tid=threadIdx.x;
  for (int i4=tid; i4<Bz*Ez/4; i4+=256){
    const int b = i4/(Ez/4), c = (i4 - b*(Ez/4))<<2;
    *(float4*)(&sLn[b][c]) = *(const float4*)(ln + b*Ez + c);
  }
  __syncthreads();
  const int wv=tid>>6, lane=tid&63, rr=lane>>4, cl=lane&15;
  const int vbase = blockIdx.x*64 + wv*16 + rr;
  float acc[4][16];
#pragma unroll
  for (int k=0;k<4;k++)
#pragma unroll
    for (int b=0;b<16;b++) acc[k][b]=0.f;

  for (int j=0;j<12;j++){
    const int c = (cl<<2) + (j<<6);
    float4 w4[4];
#pragma unroll
    for (int k=0;k<4;k++){
      const int v = vbase + 4*k;
      if (v < Vz) w4[k] = *(const float4*)(wte + (size_t)v*Ez + c);
      else { w4[k].x=w4[k].y=w4[k].z=w4[k].w=0.f; }
    }
#pragma unroll
    for (int b=0;b<16;b++){
      const float4 hv = *(const float4*)(&sLn[b][c]);
#pragma unroll
      for (int k=0;k<4;k++) acc[k][b] = dot4acc(acc[k][b], w4[k], hv);
    }
  }
#pragma unroll
  for (int off=1; off<16; off<<=1)
#pragma unroll
    for (int k=0;k<4;k++)
#pragma unroll
      for (int b=0;b<16;b++) acc[k][b] += __shfl_xor(acc[k][b], off);

  if (cl==0){
#pragma unroll
    for (int k=0;k<4;k++){
      const int v = vbase + 4*k;
      if (v < Vz){
#pragma unroll
        for (int b=0;b<16;b++) out[(size_t)b*Vz + v] = acc[k][b];
      }
    }
  }
}

extern "C" void kernel_launch(void* const* d_in, const int* in_sizes, int n_in,
                              void* d_out, int out_size, void* d_ws, size_t ws_size,
                              hipStream_t stream) {
  const int*   idx = (const int*)  d_in[0];
  const float* wte = (const float*)d_in[1];
  const float* Wih = (const float*)d_in[2];
  const float* bih = (const float*)d_in[3];
  const float* Whh = (const float*)d_in[4];
  const float* bhh = (const float*)d_in[5];
  const float* g   = (const float*)d_in[6];
  float* out = (float*)d_out;

  float* base = (float*)d_ws;
  unsigned* flags = (unsigned*)d_ws;         // words [0,256): per-block flags
  unsigned* go    = (unsigned*)d_ws + 512;   // word 512: the broadcast word
  float* h0g = base + 1024;                  // 2 * B*E
  float* h1g = h0g + 2*VEC;                  // 2 * B*E
  float* ln  = h1g + 2*VEC;                  // B*E

  (void)hipMemsetAsync(d_ws, 0, 4096, stream);  // reset flags+go each (re)play

  void* args[] = {(void*)&idx,(void*)&wte,(void*)&Wih,(void*)&bih,
                  (void*)&Whh,(void*)&bhh,(void*)&h0g,(void*)&h1g,
                  (void*)&flags,(void*)&go};
  (void)hipLaunchCooperativeKernel((void*)gru_scan, dim3(NBK), dim3(512), args, 0, stream);

  // final h1(1023) lives in h1g[(Tz-1)&1] = h1g + VEC
  finalize_ln<<<1, 256, 0, stream>>>(h1g + VEC, g, ln);
  lm_head<<<786, 256, 0, stream>>>(ln, wte, out);
}

// Round 14
// 24585.048 us; speedup vs baseline: 1.0010x; 1.0010x over previous
//
#include <hip/hip_runtime.h>
#include <math.h>

#define Bz 16
#define Tz 1024
#define Ez 768
#define E3 2304
#define Vz 50257
#define NBK 256          // 256 blocks: 128 layer-0, 128 layer-1, 6 columns each
#define LN_EPS 1e-5f
#define VEC (Bz*Ez)      // 12288 floats per h vector
#define EP 772           // padded LDS row stride

__device__ __forceinline__ float dot4acc(float acc, float4 w, float4 h){
  acc = fmaf(w.x,h.x,acc); acc = fmaf(w.y,h.y,acc);
  acc = fmaf(w.z,h.z,acc); acc = fmaf(w.w,h.w,acc);
  return acc;
}
__device__ __forceinline__ float sigm(float x){ return 1.0f/(1.0f+expf(-x)); }

// ---- Staging envelope (empirical): scalar 32-bit relaxed-atomic loads with
// immediate LDS stores, <=4 independent streams per body. Batched/asm/DMA
// variants all fail (all-zero signature). Unchanged from passing R13. ----

__device__ __forceinline__ void stage_one(const float* __restrict__ src,
                                          float (*dst)[EP], int tid){
#pragma unroll
  for (int k=0;k<6;k++){
    const int u0 = tid + (k<<9);
    const int u1 = u0 + 3072;
    const int u2 = u0 + 6144;
    const int u3 = u0 + 9216;
    const float a0 = __hip_atomic_load(src+u0, __ATOMIC_RELAXED, __HIP_MEMORY_SCOPE_AGENT);
    const float a1 = __hip_atomic_load(src+u1, __ATOMIC_RELAXED, __HIP_MEMORY_SCOPE_AGENT);
    const float a2 = __hip_atomic_load(src+u2, __ATOMIC_RELAXED, __HIP_MEMORY_SCOPE_AGENT);
    const float a3 = __hip_atomic_load(src+u3, __ATOMIC_RELAXED, __HIP_MEMORY_SCOPE_AGENT);
    const int b0=u0/768, c0_=u0-b0*768;  dst[b0][c0_]=a0;
    const int b1=u1/768, c1_=u1-b1*768;  dst[b1][c1_]=a1;
    const int b2=u2/768, c2_=u2-b2*768;  dst[b2][c2_]=a2;
    const int b3=u3/768, c3_=u3-b3*768;  dst[b3][c3_]=a3;
  }
}

__device__ __forceinline__ void stage_two(const float* __restrict__ srcX,
                                          float (*dstX)[EP],
                                          const float* __restrict__ srcH,
                                          float (*dstH)[EP], int tid){
#pragma unroll
  for (int k=0;k<12;k++){
    const int u0 = tid + (k<<9);
    const int u1 = u0 + 6144;
    const float x0 = __hip_atomic_load(srcX+u0, __ATOMIC_RELAXED, __HIP_MEMORY_SCOPE_AGENT);
    const float x1 = __hip_atomic_load(srcX+u1, __ATOMIC_RELAXED, __HIP_MEMORY_SCOPE_AGENT);
    const float h0 = __hip_atomic_load(srcH+u0, __ATOMIC_RELAXED, __HIP_MEMORY_SCOPE_AGENT);
    const float h1 = __hip_atomic_load(srcH+u1, __ATOMIC_RELAXED, __HIP_MEMORY_SCOPE_AGENT);
    const int b0=u0/768, c0_=u0-b0*768;
    const int b1=u1/768, c1_=u1-b1*768;
    dstX[b0][c0_]=x0;  dstX[b1][c1_]=x1;
    dstH[b0][c0_]=h0;  dstH[b1][c1_]=h1;
  }
}

__device__ __forceinline__ void zero_buf(float (*dst)[EP], int tid){
#pragma unroll
  for (int k=0;k<24;k++){
    const int u = tid + (k<<9);
    const int b = u/768, c = u - b*768;
    dst[b][c] = 0.f;
  }
}

// ---------------------------------------------------------------------------
// Persistent cooperative scan; layer-skewed. Two-level STORE-ONLY barrier
// with REPLICATED go lines (this round's change):
//   arrive:    flags[bx] = s+1                  (256 words, 8 lines)
//   aggregate: block 0 wave 0 polls all flags, then 64 lanes store s to
//              64 go-copies on 64 DISTINCT 128B lines (one parallel hop)
//   wait:      block bx polls ONLY go[bx&63]    (<=4 pollers/line vs 255)
// Mechanism: same-line reads serialize at the L3 slice; 255 pollers on one
// word inflated the barrier to ~15us (R12=R13 despite stage halving).
// ---------------------------------------------------------------------------
__global__ __launch_bounds__(512) void gru_scan(
    const int* __restrict__ idx, const float* __restrict__ wte,
    const float* __restrict__ Wih, const float* __restrict__ bih,
    const float* __restrict__ Whh, const float* __restrict__ bhh,
    float* __restrict__ h0g, float* __restrict__ h1g,
    unsigned* __restrict__ flags, unsigned* __restrict__ go)
{
  __shared__ float bufX0[Bz][EP];   // L0: x(t) ping   | L1: h0(t)
  __shared__ float bufX1[Bz][EP];   // L0: x(t) pong   | L1: unused
  __shared__ float bufH [Bz][EP];   // h_prev (own layer)
  __shared__ float gates[36][17];   // [row m][batch]
  __shared__ float biasS[36];

  const int tid = threadIdx.x, bx = blockIdx.x;
  const int L = bx>>7, sub = bx&127, c0 = sub*6;
  const int wv = tid>>6, lane = tid&63, kq = lane&15, bb = lane>>4;

  const float* WihL = Wih + (size_t)L*E3*Ez;
  const float* WhhL = Whh + (size_t)L*E3*Ez;

  const float* wrow[9];
#pragma unroll
  for (int r=0;r<9;r++){
    const int m = (wv&3)*9+r, mat = m/18, mm = m%18, g = mm/6, cc = mm-g*6;
    wrow[r] = (mat ? WhhL : WihL) + (size_t)(g*Ez + c0 + cc)*Ez;
  }
  if (tid<36){
    const int mat = tid/18, mm = tid%18, g = mm/6, cc = mm-g*6;
    biasS[tid] = (mat ? bhh : bih)[L*E3 + g*Ez + c0 + cc];
  }

  // preload x(0) for layer 0 (512 threads x 6 float4)
  if (L==0){
#pragma unroll
    for (int k4=0;k4<6;k4++){
      const int i4 = tid + (k4<<9);
      const int b = i4/192, c4 = i4 - b*192;
      const int row = idx[b*Tz];
      *(float4*)&bufX0[b][c4<<2] = *(const float4*)(wte + (size_t)row*Ez + (c4<<2));
    }
  }
  __syncthreads();

  for (int s=0; s<=Tz; ++s){
    // ---- grid wait ----
    if (s>0){
      const unsigned tgt = (unsigned)s;
      if (bx==0){
        if (tid<64){
          const unsigned* f = flags + (tid<<2);
          for(;;){
            const unsigned a0 = __hip_atomic_load(f+0, __ATOMIC_RELAXED, __HIP_MEMORY_SCOPE_AGENT);
            const unsigned a1 = __hip_atomic_load(f+1, __ATOMIC_RELAXED, __HIP_MEMORY_SCOPE_AGENT);
            const unsigned a2 = __hip_atomic_load(f+2, __ATOMIC_RELAXED, __HIP_MEMORY_SCOPE_AGENT);
            const unsigned a3 = __hip_atomic_load(f+3, __ATOMIC_RELAXED, __HIP_MEMORY_SCOPE_AGENT);
            const int ok = (a0>=tgt) & (a1>=tgt) & (a2>=tgt) & (a3>=tgt);
            if (__all(ok)) break;
            __builtin_amdgcn_s_sleep(1);
          }
          // broadcast: 64 lanes write 64 go-copies on distinct lines
          __hip_atomic_store(go + (tid<<5), tgt,
                             __ATOMIC_RELAXED, __HIP_MEMORY_SCOPE_AGENT);
        }
      } else {
        if (tid==0){
          const unsigned* gp = go + ((bx&63)<<5);
          while (__hip_atomic_load(gp, __ATOMIC_RELAXED, __HIP_MEMORY_SCOPE_AGENT) < tgt)
            __builtin_amdgcn_s_sleep(2);
        }
      }
      __syncthreads();
    }

    const bool active = (L==0) ? (s<Tz) : (s>0);
    if (active){
      const int t = (L==0) ? s : s-1;

      // ---- stage phase (512 threads, 4-wide immediate-store bodies) ----
      if (L==0){
        if (t==0) zero_buf(bufH, tid);
        else      stage_one(h0g + (size_t)((s-1)&1)*VEC, bufH, tid);
      } else {
        if (t==0){
          stage_one(h0g + (size_t)((s-1)&1)*VEC, bufX0, tid);
          zero_buf(bufH, tid);
        } else {
          stage_two(h0g + (size_t)((s-1)&1)*VEC, bufX0,
                    h1g + (size_t)(s&1)*VEC,     bufH, tid);
        }
      }
      __syncthreads();

      // ---- matmul on waves 0-3 only ----
      if (tid < 256){
        const float (*V)[EP];
        if (wv<2) V = (L==0) ? ((s&1) ? bufX1 : bufX0) : bufX0;
        else      V = bufH;

        float acc[9][4];
#pragma unroll
        for (int r=0;r<9;r++)
#pragma unroll
          for (int bi=0;bi<4;bi++) acc[r][bi]=0.f;

#pragma unroll 4
        for (int j=0;j<12;j++){
          const int kk = (j<<6) + (kq<<2);
          float4 wv4[9];
#pragma unroll
          for (int r=0;r<9;r++) wv4[r] = *(const float4*)(wrow[r] + kk);
#pragma unroll
          for (int bi=0;bi<4;bi++){
            const float4 hv = *(const float4*)&V[bb*4+bi][kk];
#pragma unroll
            for (int r=0;r<9;r++) acc[r][bi] = dot4acc(acc[r][bi], wv4[r], hv);
          }
        }
#pragma unroll
        for (int r=0;r<9;r++)
#pragma unroll
          for (int bi=0;bi<4;bi++){
            float a = acc[r][bi];
            a += __shfl_xor(a,1); a += __shfl_xor(a,2);
            a += __shfl_xor(a,4); a += __shfl_xor(a,8);
            acc[r][bi]=a;
          }
        if (kq==0){
#pragma unroll
          for (int r=0;r<9;r++)
#pragma unroll
            for (int bi=0;bi<4;bi++) gates[wv*9+r][bb*4+bi] = acc[r][bi];
        }
      }
      __syncthreads();

      // ---- nonlinearity + publish h-slice (96 threads: 16 b x 6 cols) ----
      if (tid < 96){
        const int b = tid&15, cc = tid>>4;
        const float gir = gates[cc   ][b] + biasS[cc];
        const float giz = gates[6+cc ][b] + biasS[6+cc];
        const float gin = gates[12+cc][b] + biasS[12+cc];
        const float ghr = gates[18+cc][b] + biasS[18+cc];
        const float ghz = gates[24+cc][b] + biasS[24+cc];
        const float ghn = gates[30+cc][b] + biasS[30+cc];
        const float r = sigm(gir+ghr);
        const float z = sigm(giz+ghz);
        const float n = tanhf(fmaf(r, ghn, gin));
        const float hp = bufH[b][c0+cc];
        const float hv = fmaf(z, hp - n, n);
        float* hOut = (L==0) ? (h0g + (size_t)(s&1)*VEC)
                             : (h1g + (size_t)((s-1)&1)*VEC);
        __hip_atomic_store(hOut + b*Ez + c0 + cc, hv,
                           __ATOMIC_RELAXED, __HIP_MEMORY_SCOPE_AGENT);
      }
    }

    // ---- arrive: syncthreads drains vmcnt (h stores at L3), then flag ----
    __syncthreads();
    if (tid==0)
      __hip_atomic_store(flags + bx, (unsigned)(s+1),
                         __ATOMIC_RELAXED, __HIP_MEMORY_SCOPE_AGENT);

    // ---- prefetch x(s+1) AFTER arrive (off the barrier critical path) ----
    if (L==0 && active && s+1 < Tz){
      float (*bx_)[EP] = ((s+1)&1) ? bufX1 : bufX0;
#pragma unroll
      for (int k4=0;k4<6;k4++){
        const int i4 = tid + (k4<<9);
        const int b = i4/192, c4 = i4 - b*192;
        const int row = idx[b*Tz + (s+1)];
        *(float4*)&bx_[b][c4<<2] = *(const float4*)(wte + (size_t)row*Ez + (c4<<2));
      }
    }
  }
}

// LayerNorm of final h1 -> ln
__global__ __launch_bounds__(256) void finalize_ln(
    const float* __restrict__ h1, const float* __restrict__ g,
    float* __restrict__ ln)
{
  const int tid=threadIdx.x, wv=tid>>6, lane=tid&63;
  for (int b=wv; b<Bz; b+=4){
    float sum=0.f;
    for (int c=lane;c<Ez;c+=64) sum += h1[b*Ez+c];
#pragma unroll
    for (int off=32; off; off>>=1) sum += __shfl_xor(sum, off);
    const float mu = sum/(float)Ez;
    float s2=0.f;
    for (int c=lane;c<Ez;c+=64){ const float d=h1[b*Ez+c]-mu; s2=fmaf(d,d,s2); }
#pragma unroll
    for (int off=32; off; off>>=1) s2 += __shfl_xor(s2, off);
    const float inv = rsqrtf(s2/(float)Ez + LN_EPS);
    for (int c=lane;c<Ez;c+=64) ln[b*Ez+c] = (h1[b*Ez+c]-mu)*inv*g[c];
  }
}

// logits[b,v] = dot(ln[b,:], wte[v,:]) ; 64 rows per block, 16 rows per wave.
__global__ __launch_bounds__(256) void lm_head(
    const float* __restrict__ ln, const float* __restrict__ wte,
    float* __restrict__ out)
{
  __shared__ float sLn[Bz][EP];
  const int tid=threadIdx.x;
  for (int i4=tid; i4<Bz*Ez/4; i4+=256){
    const int b = i4/(Ez/4), c = (i4 - b*(Ez/4))<<2;
    *(float4*)(&sLn[b][c]) = *(const float4*)(ln + b*Ez + c);
  }
  __syncthreads();
  const int wv=tid>>6, lane=tid&63, rr=lane>>4, cl=lane&15;
  const int vbase = blockIdx.x*64 + wv*16 + rr;
  float acc[4][16];
#pragma unroll
  for (int k=0;k<4;k++)
#pragma unroll
    for (int b=0;b<16;b++) acc[k][b]=0.f;

  for (int j=0;j<12;j++){
    const int c = (cl<<2) + (j<<6);
    float4 w4[4];
#pragma unroll
    for (int k=0;k<4;k++){
      const int v = vbase + 4*k;
      if (v < Vz) w4[k] = *(const float4*)(wte + (size_t)v*Ez + c);
      else { w4[k].x=w4[k].y=w4[k].z=w4[k].w=0.f; }
    }
#pragma unroll
    for (int b=0;b<16;b++){
      const float4 hv = *(const float4*)(&sLn[b][c]);
#pragma unroll
      for (int k=0;k<4;k++) acc[k][b] = dot4acc(acc[k][b], w4[k], hv);
    }
  }
#pragma unroll
  for (int off=1; off<16; off<<=1)
#pragma unroll
    for (int k=0;k<4;k++)
#pragma unroll
      for (int b=0;b<16;b++) acc[k][b] += __shfl_xor(acc[k][b], off);

  if (cl==0){
#pragma unroll
    for (int k=0;k<4;k++){
      const int v = vbase + 4*k;
      if (v < Vz){
#pragma unroll
        for (int b=0;b<16;b++) out[(size_t)b*Vz + v] = acc[k][b];
      }
    }
  }
}

extern "C" void kernel_launch(void* const* d_in, const int* in_sizes, int n_in,
                              void* d_out, int out_size, void* d_ws, size_t ws_size,
                              hipStream_t stream) {
  const int*   idx = (const int*)  d_in[0];
  const float* wte = (const float*)d_in[1];
  const float* Wih = (const float*)d_in[2];
  const float* bih = (const float*)d_in[3];
  const float* Whh = (const float*)d_in[4];
  const float* bhh = (const float*)d_in[5];
  const float* g   = (const float*)d_in[6];
  float* out = (float*)d_out;

  float* base = (float*)d_ws;
  unsigned* flags = (unsigned*)d_ws;         // words [0,256): per-block flags
  unsigned* go    = (unsigned*)d_ws + 512;   // words [512,2560): 64 go-copies, 128B apart
  float* h0g = base + 4096;                  // 2 * B*E
  float* h1g = h0g + 2*VEC;                  // 2 * B*E
  float* ln  = h1g + 2*VEC;                  // B*E

  (void)hipMemsetAsync(d_ws, 0, 16384, stream);  // reset flags + go-copies

  void* args[] = {(void*)&idx,(void*)&wte,(void*)&Wih,(void*)&bih,
                  (void*)&Whh,(void*)&bhh,(void*)&h0g,(void*)&h1g,
                  (void*)&flags,(void*)&go};
  (void)hipLaunchCooperativeKernel((void*)gru_scan, dim3(NBK), dim3(512), args, 0, stream);

  // final h1(1023) lives in h1g[(Tz-1)&1] = h1g + VEC
  finalize_ln<<<1, 256, 0, stream>>>(h1g + VEC, g, ln);
  lm_head<<<786, 256, 0, stream>>>(ln, wte, out);
}

// Round 15
// 18205.405 us; speedup vs baseline: 1.3518x; 1.3504x over previous
//
#include <hip/hip_runtime.h>
#include <hip/hip_fp16.h>
#include <math.h>

#define Bz 16
#define Tz 1024
#define Ez 768
#define E3 2304
#define Vz 50257
#define NBK 256          // 256 blocks: 128 layer-0, 128 layer-1, 6 columns each
#define LN_EPS 1e-5f
#define VEC (Bz*Ez)      // 12288 floats per h vector
#define VECW 6144        // packed fp16: u32 words per h vector
#define EP 772           // padded LDS row stride

__device__ __forceinline__ float dot4acc(float acc, float4 w, float4 h){
  acc = fmaf(w.x,h.x,acc); acc = fmaf(w.y,h.y,acc);
  acc = fmaf(w.z,h.z,acc); acc = fmaf(w.w,h.w,acc);
  return acc;
}
__device__ __forceinline__ float sigm(float x){ return 1.0f/(1.0f+expf(-x)); }

__device__ __forceinline__ unsigned pack2(float a, float b){
  __half2 h = __floats2half2_rn(a, b);
  union{__half2 h2; unsigned u;} cv; cv.h2 = h; return cv.u;
}
__device__ __forceinline__ float2 unpack2(unsigned u){
  union{unsigned u; __half2 h2;} cv; cv.u = u;
  return __half22float2(cv.h2);
}

// ---- Staging envelope (empirical): scalar 32-bit relaxed-atomic loads with
// immediate LDS stores, <=4 outstanding per body. Batched(>=8)/asm/DMA all
// fail (zero-fixed-point signature). fp16 packing: 1 u32 = 2 h values. ----

// One packed vector (6144 u32), 512 threads -> 12 words/thread, 3 bodies x4.
__device__ __forceinline__ void stage_one_h(const unsigned* __restrict__ src,
                                            float (*dst)[EP], int tid){
#pragma unroll
  for (int k=0;k<3;k++){
    const int u0 = tid + (k<<9);
    const int u1 = u0 + 1536;
    const int u2 = u0 + 3072;
    const int u3 = u0 + 4608;
    const unsigned a0 = __hip_atomic_load(src+u0, __ATOMIC_RELAXED, __HIP_MEMORY_SCOPE_AGENT);
    const unsigned a1 = __hip_atomic_load(src+u1, __ATOMIC_RELAXED, __HIP_MEMORY_SCOPE_AGENT);
    const unsigned a2 = __hip_atomic_load(src+u2, __ATOMIC_RELAXED, __HIP_MEMORY_SCOPE_AGENT);
    const unsigned a3 = __hip_atomic_load(src+u3, __ATOMIC_RELAXED, __HIP_MEMORY_SCOPE_AGENT);
    {const int b=u0/384, c=(u0-b*384)<<1; const float2 f=unpack2(a0); dst[b][c]=f.x; dst[b][c+1]=f.y;}
    {const int b=u1/384, c=(u1-b*384)<<1; const float2 f=unpack2(a1); dst[b][c]=f.x; dst[b][c+1]=f.y;}
    {const int b=u2/384, c=(u2-b*384)<<1; const float2 f=unpack2(a2); dst[b][c]=f.x; dst[b][c+1]=f.y;}
    {const int b=u3/384, c=(u3-b*384)<<1; const float2 f=unpack2(a3); dst[b][c]=f.x; dst[b][c+1]=f.y;}
  }
}

// Two packed vectors -> two buffers, 6 bodies x 4 loads (2 per vector).
__device__ __forceinline__ void stage_two_h(const unsigned* __restrict__ srcX,
                                            float (*dstX)[EP],
                                            const unsigned* __restrict__ srcH,
                                            float (*dstH)[EP], int tid){
#pragma unroll
  for (int k=0;k<6;k++){
    const int u0 = tid + (k<<9);
    const int u1 = u0 + 3072;
    const unsigned x0 = __hip_atomic_load(srcX+u0, __ATOMIC_RELAXED, __HIP_MEMORY_SCOPE_AGENT);
    const unsigned x1 = __hip_atomic_load(srcX+u1, __ATOMIC_RELAXED, __HIP_MEMORY_SCOPE_AGENT);
    const unsigned h0 = __hip_atomic_load(srcH+u0, __ATOMIC_RELAXED, __HIP_MEMORY_SCOPE_AGENT);
    const unsigned h1 = __hip_atomic_load(srcH+u1, __ATOMIC_RELAXED, __HIP_MEMORY_SCOPE_AGENT);
    const int b0=u0/384, c0_=(u0-b0*384)<<1;
    const int b1=u1/384, c1_=(u1-b1*384)<<1;
    {const float2 f=unpack2(x0); dstX[b0][c0_]=f.x; dstX[b0][c0_+1]=f.y;}
    {const float2 f=unpack2(x1); dstX[b1][c1_]=f.x; dstX[b1][c1_+1]=f.y;}
    {const float2 f=unpack2(h0); dstH[b0][c0_]=f.x; dstH[b0][c0_+1]=f.y;}
    {const float2 f=unpack2(h1); dstH[b1][c1_]=f.x; dstH[b1][c1_+1]=f.y;}
  }
}

__device__ __forceinline__ void zero_buf(float (*dst)[EP], int tid){
#pragma unroll
  for (int k=0;k<24;k++){
    const int u = tid + (k<<9);
    const int b = u/768, c = u - b*768;
    dst[b][c] = 0.f;
  }
}

// ---------------------------------------------------------------------------
// Persistent cooperative scan; layer-skewed. Barrier = R14 (flags + block-0
// aggregate + 64 replicated go lines), all 32-bit relaxed agent atomics.
// THIS ROUND: h exchange in packed fp16 (u32 = 2 cols) -> halves the UC
// fabric traffic that R12-R14 proved is the binding resource (787 GB/s,
// 18.9 MB/step = 24.0us = measured step). Recurrence precision preserved via
// per-block PRIVATE fp32 hprev[16][6] (fp16 only taints matmul operands).
// ---------------------------------------------------------------------------
__global__ __launch_bounds__(512) void gru_scan(
    const int* __restrict__ idx, const float* __restrict__ wte,
    const float* __restrict__ Wih, const float* __restrict__ bih,
    const float* __restrict__ Whh, const float* __restrict__ bhh,
    unsigned* __restrict__ h0g, unsigned* __restrict__ h1g,
    float* __restrict__ h1f,
    unsigned* __restrict__ flags, unsigned* __restrict__ go)
{
  __shared__ float bufX0[Bz][EP];   // L0: x(t) ping   | L1: h0(t)
  __shared__ float bufX1[Bz][EP];   // L0: x(t) pong   | L1: unused
  __shared__ float bufH [Bz][EP];   // h_prev (own layer, fp16-rounded)
  __shared__ float gates[36][17];   // [row m][batch]
  __shared__ float biasS[36];
  __shared__ float hprev[Bz][6];    // own columns' h, exact fp32, persists

  const int tid = threadIdx.x, bx = blockIdx.x;
  const int L = bx>>7, sub = bx&127, c0 = sub*6;
  const int wv = tid>>6, lane = tid&63, kq = lane&15, bb = lane>>4;

  const float* WihL = Wih + (size_t)L*E3*Ez;
  const float* WhhL = Whh + (size_t)L*E3*Ez;

  const float* wrow[9];
#pragma unroll
  for (int r=0;r<9;r++){
    const int m = (wv&3)*9+r, mat = m/18, mm = m%18, g = mm/6, cc = mm-g*6;
    wrow[r] = (mat ? WhhL : WihL) + (size_t)(g*Ez + c0 + cc)*Ez;
  }
  if (tid<36){
    const int mat = tid/18, mm = tid%18, g = mm/6, cc = mm-g*6;
    biasS[tid] = (mat ? bhh : bih)[L*E3 + g*Ez + c0 + cc];
  }
  if (tid<96) hprev[tid&15][tid>>4] = 0.f;

  // preload x(0) for layer 0 (512 threads x 6 float4)
  if (L==0){
#pragma unroll
    for (int k4=0;k4<6;k4++){
      const int i4 = tid + (k4<<9);
      const int b = i4/192, c4 = i4 - b*192;
      const int row = idx[b*Tz];
      *(float4*)&bufX0[b][c4<<2] = *(const float4*)(wte + (size_t)row*Ez + (c4<<2));
    }
  }
  __syncthreads();

  for (int s=0; s<=Tz; ++s){
    // ---- grid wait (R14 barrier, unchanged) ----
    if (s>0){
      const unsigned tgt = (unsigned)s;
      if (bx==0){
        if (tid<64){
          const unsigned* f = flags + (tid<<2);
          for(;;){
            const unsigned a0 = __hip_atomic_load(f+0, __ATOMIC_RELAXED, __HIP_MEMORY_SCOPE_AGENT);
            const unsigned a1 = __hip_atomic_load(f+1, __ATOMIC_RELAXED, __HIP_MEMORY_SCOPE_AGENT);
            const unsigned a2 = __hip_atomic_load(f+2, __ATOMIC_RELAXED, __HIP_MEMORY_SCOPE_AGENT);
            const unsigned a3 = __hip_atomic_load(f+3, __ATOMIC_RELAXED, __HIP_MEMORY_SCOPE_AGENT);
            const int ok = (a0>=tgt) & (a1>=tgt) & (a2>=tgt) & (a3>=tgt);
            if (__all(ok)) break;
            __builtin_amdgcn_s_sleep(1);
          }
          __hip_atomic_store(go + (tid<<5), tgt,
                             __ATOMIC_RELAXED, __HIP_MEMORY_SCOPE_AGENT);
        }
      } else {
        if (tid==0){
          const unsigned* gp = go + ((bx&63)<<5);
          while (__hip_atomic_load(gp, __ATOMIC_RELAXED, __HIP_MEMORY_SCOPE_AGENT) < tgt)
            __builtin_amdgcn_s_sleep(2);
        }
      }
      __syncthreads();
    }

    const bool active = (L==0) ? (s<Tz) : (s>0);
    if (active){
      const int t = (L==0) ? s : s-1;

      // ---- stage phase (packed fp16 -> fp32 LDS) ----
      if (L==0){
        if (t==0) zero_buf(bufH, tid);
        else      stage_one_h(h0g + (size_t)((s-1)&1)*VECW, bufH, tid);
      } else {
        if (t==0){
          stage_one_h(h0g + (size_t)((s-1)&1)*VECW, bufX0, tid);
          zero_buf(bufH, tid);
        } else {
          stage_two_h(h0g + (size_t)((s-1)&1)*VECW, bufX0,
                      h1g + (size_t)(s&1)*VECW,     bufH, tid);
        }
      }
      __syncthreads();

      // ---- matmul on waves 0-3 only ----
      if (tid < 256){
        const float (*V)[EP];
        if (wv<2) V = (L==0) ? ((s&1) ? bufX1 : bufX0) : bufX0;
        else      V = bufH;

        float acc[9][4];
#pragma unroll
        for (int r=0;r<9;r++)
#pragma unroll
          for (int bi=0;bi<4;bi++) acc[r][bi]=0.f;

#pragma unroll 4
        for (int j=0;j<12;j++){
          const int kk = (j<<6) + (kq<<2);
          float4 wv4[9];
#pragma unroll
          for (int r=0;r<9;r++) wv4[r] = *(const float4*)(wrow[r] + kk);
#pragma unroll
          for (int bi=0;bi<4;bi++){
            const float4 hv = *(const float4*)&V[bb*4+bi][kk];
#pragma unroll
            for (int r=0;r<9;r++) acc[r][bi] = dot4acc(acc[r][bi], wv4[r], hv);
          }
        }
#pragma unroll
        for (int r=0;r<9;r++)
#pragma unroll
          for (int bi=0;bi<4;bi++){
            float a = acc[r][bi];
            a += __shfl_xor(a,1); a += __shfl_xor(a,2);
            a += __shfl_xor(a,4); a += __shfl_xor(a,8);
            acc[r][bi]=a;
          }
        if (kq==0){
#pragma unroll
          for (int r=0;r<9;r++)
#pragma unroll
            for (int bi=0;bi<4;bi++) gates[wv*9+r][bb*4+bi] = acc[r][bi];
        }
      }
      __syncthreads();

      // ---- nonlinearity + publish (48 threads: 16 b x 3 col-pairs) ----
      if (tid < 48){
        const int b = tid&15, j = tid>>4;      // pair j: cols 2j, 2j+1
        float hv2[2];
#pragma unroll
        for (int e=0;e<2;e++){
          const int cc = 2*j+e;
          const float gir = gates[cc   ][b] + biasS[cc];
          const float giz = gates[6+cc ][b] + biasS[6+cc];
          const float gin = gates[12+cc][b] + biasS[12+cc];
          const float ghr = gates[18+cc][b] + biasS[18+cc];
          const float ghz = gates[24+cc][b] + biasS[24+cc];
          const float ghn = gates[30+cc][b] + biasS[30+cc];
          const float r = sigm(gir+ghr);
          const float z = sigm(giz+ghz);
          const float n = tanhf(fmaf(r, ghn, gin));
          const float hp = hprev[b][cc];       // exact fp32 private state
          hv2[e] = fmaf(z, hp - n, n);
          hprev[b][cc] = hv2[e];
        }
        unsigned* hOutW = (L==0) ? (h0g + (size_t)(s&1)*VECW)
                                 : (h1g + (size_t)((s-1)&1)*VECW);
        const unsigned pk = pack2(hv2[0], hv2[1]);
        __hip_atomic_store(hOutW + b*384 + sub*3 + j, pk,
                           __ATOMIC_RELAXED, __HIP_MEMORY_SCOPE_AGENT);
        if (L==1 && t==Tz-1){                  // final h1 in fp32 for LN
          h1f[b*Ez + c0 + 2*j    ] = hv2[0];
          h1f[b*Ez + c0 + 2*j + 1] = hv2[1];
        }
      }
    }

    // ---- arrive: syncthreads drains vmcnt, then flag ----
    __syncthreads();
    if (tid==0)
      __hip_atomic_store(flags + bx, (unsigned)(s+1),
                         __ATOMIC_RELAXED, __HIP_MEMORY_SCOPE_AGENT);

    // ---- prefetch x(s+1) AFTER arrive ----
    if (L==0 && active && s+1 < Tz){
      float (*bx_)[EP] = ((s+1)&1) ? bufX1 : bufX0;
#pragma unroll
      for (int k4=0;k4<6;k4++){
        const int i4 = tid + (k4<<9);
        const int b = i4/192, c4 = i4 - b*192;
        const int row = idx[b*Tz + (s+1)];
        *(float4*)&bx_[b][c4<<2] = *(const float4*)(wte + (size_t)row*Ez + (c4<<2));
      }
    }
  }
}

// LayerNorm of final h1 (fp32) -> ln
__global__ __launch_bounds__(256) void finalize_ln(
    const float* __restrict__ h1, const float* __restrict__ g,
    float* __restrict__ ln)
{
  const int tid=threadIdx.x, wv=tid>>6, lane=tid&63;
  for (int b=wv; b<Bz; b+=4){
    float sum=0.f;
    for (int c=lane;c<Ez;c+=64) sum += h1[b*Ez+c];
#pragma unroll
    for (int off=32; off; off>>=1) sum += __shfl_xor(sum, off);
    const float mu = sum/(float)Ez;
    float s2=0.f;
    for (int c=lane;c<Ez;c+=64){ const float d=h1[b*Ez+c]-mu; s2=fmaf(d,d,s2); }
#pragma unroll
    for (int off=32; off; off>>=1) s2 += __shfl_xor(s2, off);
    const float inv = rsqrtf(s2/(float)Ez + LN_EPS);
    for (int c=lane;c<Ez;c+=64) ln[b*Ez+c] = (h1[b*Ez+c]-mu)*inv*g[c];
  }
}

// logits[b,v] = dot(ln[b,:], wte[v,:]) ; 64 rows per block, 16 rows per wave.
__global__ __launch_bounds__(256) void lm_head(
    const float* __restrict__ ln, const float* __restrict__ wte,
    float* __restrict__ out)
{
  __shared__ float sLn[Bz][EP];
  const int tid=threadIdx.x;
  for (int i4=tid; i4<Bz*Ez/4; i4+=256){
    const int b = i4/(Ez/4), c = (i4 - b*(Ez/4))<<2;
    *(float4*)(&sLn[b][c]) = *(const float4*)(ln + b*Ez + c);
  }
  __syncthreads();
  const int wv=tid>>6, lane=tid&63, rr=lane>>4, cl=lane&15;
  const int vbase = blockIdx.x*64 + wv*16 + rr;
  float acc[4][16];
#pragma unroll
  for (int k=0;k<4;k++)
#pragma unroll
    for (int b=0;b<16;b++) acc[k][b]=0.f;

  for (int j=0;j<12;j++){
    const int c = (cl<<2) + (j<<6);
    float4 w4[4];
#pragma unroll
    for (int k=0;k<4;k++){
      const int v = vbase + 4*k;
      if (v < Vz) w4[k] = *(const float4*)(wte + (size_t)v*Ez + c);
      else { w4[k].x=w4[k].y=w4[k].z=w4[k].w=0.f; }
    }
#pragma unroll
    for (int b=0;b<16;b++){
      const float4 hv = *(const float4*)(&sLn[b][c]);
#pragma unroll
      for (int k=0;k<4;k++) acc[k][b] = dot4acc(acc[k][b], w4[k], hv);
    }
  }
#pragma unroll
  for (int off=1; off<16; off<<=1)
#pragma unroll
    for (int k=0;k<4;k++)
#pragma unroll
      for (int b=0;b<16;b++) acc[k][b] += __shfl_xor(acc[k][b], off);

  if (cl==0){
#pragma unroll
    for (int k=0;k<4;k++){
      const int v = vbase + 4*k;
      if (v < Vz){
#pragma unroll
        for (int b=0;b<16;b++) out[(size_t)b*Vz + v] = acc[k][b];
      }
    }
  }
}

extern "C" void kernel_launch(void* const* d_in, const int* in_sizes, int n_in,
                              void* d_out, int out_size, void* d_ws, size_t ws_size,
                              hipStream_t stream) {
  const int*   idx = (const int*)  d_in[0];
  const float* wte = (const float*)d_in[1];
  const float* Wih = (const float*)d_in[2];
  const float* bih = (const float*)d_in[3];
  const float* Whh = (const float*)d_in[4];
  const float* bhh = (const float*)d_in[5];
  const float* g   = (const float*)d_in[6];
  float* out = (float*)d_out;

  unsigned* flags = (unsigned*)d_ws;            // words [0,256)
  unsigned* go    = (unsigned*)d_ws + 512;      // words [512,2560): 64 lines
  unsigned* h0g   = (unsigned*)d_ws + 4096;     // 2 x 6144 words (fp16 pairs)
  unsigned* h1g   = h0g + 2*VECW;               // 2 x 6144 words
  float*    h1f   = (float*)(h1g + 2*VECW);     // B*E fp32 final h1
  float*    ln    = h1f + VEC;                  // B*E fp32

  (void)hipMemsetAsync(d_ws, 0, 16384, stream); // reset flags + go lines

  void* args[] = {(void*)&idx,(void*)&wte,(void*)&Wih,(void*)&bih,
                  (void*)&Whh,(void*)&bhh,(void*)&h0g,(void*)&h1g,
                  (void*)&h1f,(void*)&flags,(void*)&go};
  (void)hipLaunchCooperativeKernel((void*)gru_scan, dim3(NBK), dim3(512), args, 0, stream);

  finalize_ln<<<1, 256, 0, stream>>>(h1f, g, ln);
  lm_head<<<786, 256, 0, stream>>>(ln, wte, out);
}